// Round 9
// baseline (711.567 us; speedup 1.0000x reference)
//
#include <hip/hip_runtime.h>
#include <stdint.h>

// VectorQuantizer — z:(16,256,64,64) f32 -> 65536 rows of 256; emb:(1024,256) f32.
// d_out: q[16777216] | vq_loss[1] | idx_as_float[65536]
//
// R9: MFMA argmin. dot = zh·eh + zh·el + zl·eh (bf16 hi/lo split, err ~1e-5)
// + exact-fp32 fixup for rows with margin < 2e-3 (expected ~30 rows).
// A (z) in swizzled LDS; B (e) streamed from L2. 2 blocks/CU, 4 waves/SIMD.

typedef __attribute__((ext_vector_type(8))) short short8;
typedef __attribute__((ext_vector_type(4))) float f32x4;

__device__ __forceinline__ unsigned short f2bf(float f) {
    const unsigned int x = __float_as_uint(f);
    return (unsigned short)((x + 0x7FFFu + ((x >> 16) & 1u)) >> 16);
}
__device__ __forceinline__ float bf2f(unsigned short h) {
    return __uint_as_float(((unsigned int)h) << 16);
}

// ---------------- kernel 0: e prep — eh/el bf16 split + fp32 norms ----------------
__global__ __launch_bounds__(256)
void eprep_kernel(const float* __restrict__ emb, unsigned short* __restrict__ eh_g,
                  unsigned short* __restrict__ el_g, float* __restrict__ enorm) {
    const int code = blockIdx.x;
    const int t = threadIdx.x;
    const float v = emb[code * 256 + t];
    const unsigned short h = f2bf(v);
    eh_g[code * 256 + t] = h;
    el_g[code * 256 + t] = f2bf(v - bf2f(h));
    float s = v * v;
#pragma unroll
    for (int o = 32; o > 0; o >>= 1) s += __shfl_xor(s, o);
    __shared__ float red[4];
    if ((t & 63) == 0) red[t >> 6] = s;
    __syncthreads();
    if (t == 0) enorm[code] = (red[0] + red[1]) + (red[2] + red[3]);
}

// ---------------- kernel 1: MFMA argmin ----------------
// 512 thr = 8 waves; block = 64 rows. wave w: rowtile rt=w&3 (16 rows),
// code-half hf=w>>2 (512 codes). Chunk = 64 codes = 4 C-frags; K=256 in 8
// steps of 32; per step 3 MFMA per frag (hh, hl, lh).
#define UPDR(DIST, CODE, B1, I1, B2) { \
    const bool lt_ = (DIST) < B1; \
    B2 = lt_ ? B1 : fminf(B2, (DIST)); \
    I1 = lt_ ? (CODE) : I1; \
    B1 = lt_ ? (DIST) : B1; }

#define RED16(B1, I1, B2) \
    _Pragma("unroll") \
    for (int off_ = 1; off_ < 16; off_ <<= 1) { \
        const float ob1_ = __shfl_xor(B1, off_); \
        const int   oi1_ = __shfl_xor(I1, off_); \
        const float ob2_ = __shfl_xor(B2, off_); \
        B2 = fminf(fminf(B2, ob2_), fmaxf(B1, ob1_)); \
        const bool tk_ = (ob1_ < B1) || (ob1_ == B1 && oi1_ < I1); \
        B1 = tk_ ? ob1_ : B1; \
        I1 = tk_ ? oi1_ : I1; }

__global__ __launch_bounds__(512, 4)
void argmin_kernel(const float* __restrict__ z, const unsigned short* __restrict__ eh_g,
                   const unsigned short* __restrict__ el_g, const float* __restrict__ enorm_g,
                   float* __restrict__ idx_out, float* __restrict__ margin_out) {
    __shared__ unsigned short zh_lds[16384];   // [row][k] halfwords, idx ^ ((row&7)<<3)
    __shared__ unsigned short zl_lds[16384];
    __shared__ float znbuf[64];
    __shared__ float mb1[64];
    __shared__ int   mi1[64];
    __shared__ float mb2[64];

    const int tid = threadIdx.x;
    const int w = tid >> 6, l = tid & 63;
    const float* zblk = z + (size_t)blockIdx.x * 16384;

    // ---- stage + split z into bf16 hi/lo LDS (swizzled) ----
#pragma unroll
    for (int i = 0; i < 8; ++i) {
        const int idx = tid * 4 + i * 2048;
        const int row = idx >> 8, k = idx & 255;
        const float4 v = *reinterpret_cast<const float4*>(zblk + idx);
        const int hw = (row * 256 + k) ^ ((row & 7) << 3);
        ushort4 hv, lv;
        hv.x = f2bf(v.x); lv.x = f2bf(v.x - bf2f(hv.x));
        hv.y = f2bf(v.y); lv.y = f2bf(v.y - bf2f(hv.y));
        hv.z = f2bf(v.z); lv.z = f2bf(v.z - bf2f(hv.z));
        hv.w = f2bf(v.w); lv.w = f2bf(v.w - bf2f(hv.w));
        *reinterpret_cast<ushort4*>(&zh_lds[hw]) = hv;
        *reinterpret_cast<ushort4*>(&zl_lds[hw]) = lv;
    }
    // ---- per-row |z|^2 (fp32, from global — L2/L3 hot) ----
#pragma unroll
    for (int it = 0; it < 8; ++it) {
        const int r = it * 8 + w;
        const float4 v = *reinterpret_cast<const float4*>(zblk + r * 256 + l * 4);
        float s = fmaf(v.x, v.x, fmaf(v.y, v.y, fmaf(v.z, v.z, v.w * v.w)));
#pragma unroll
        for (int o = 32; o > 0; o >>= 1) s += __shfl_xor(s, o);
        if (l == 0) znbuf[r] = s;
    }
    __syncthreads();

    const int rt = w & 3;             // row tile (16 rows)
    const int hf = w >> 2;            // code half (512 codes)
    const int g  = l >> 4;            // k-group
    const int rowL = rt * 16 + (l & 15);
    const int abase = rowL * 256;
    const int aswz  = (rowL & 7) << 3;
    const int row0  = rt * 16 + g * 4;
    const float zn0 = znbuf[row0 + 0];
    const float zn1 = znbuf[row0 + 1];
    const float zn2 = znbuf[row0 + 2];
    const float zn3 = znbuf[row0 + 3];

    float b1_0 = 3.4e38f, b1_1 = 3.4e38f, b1_2 = 3.4e38f, b1_3 = 3.4e38f;
    float b2_0 = 3.4e38f, b2_1 = 3.4e38f, b2_2 = 3.4e38f, b2_3 = 3.4e38f;
    int   i1_0 = 0, i1_1 = 0, i1_2 = 0, i1_3 = 0;

#pragma unroll 1
    for (int ch = 0; ch < 8; ++ch) {
        const int code0 = hf * 512 + ch * 64;
        f32x4 acc0 = {0.f, 0.f, 0.f, 0.f};
        f32x4 acc1 = {0.f, 0.f, 0.f, 0.f};
        f32x4 acc2 = {0.f, 0.f, 0.f, 0.f};
        f32x4 acc3 = {0.f, 0.f, 0.f, 0.f};
        const unsigned short* ehp = eh_g + (size_t)(code0 + (l & 15)) * 256 + g * 8;
        const unsigned short* elp = el_g + (size_t)(code0 + (l & 15)) * 256 + g * 8;
#pragma unroll
        for (int s = 0; s < 8; ++s) {
            const int ka = s * 32 + g * 8;
            const short8 ah = *reinterpret_cast<const short8*>(&zh_lds[(abase + ka) ^ aswz]);
            const short8 al = *reinterpret_cast<const short8*>(&zl_lds[(abase + ka) ^ aswz]);
#define STEP(CG) { \
            const short8 bh = *reinterpret_cast<const short8*>(ehp + (CG) * 4096 + s * 32); \
            const short8 bl = *reinterpret_cast<const short8*>(elp + (CG) * 4096 + s * 32); \
            acc##CG = __builtin_amdgcn_mfma_f32_16x16x32_bf16(ah, bh, acc##CG, 0, 0, 0); \
            acc##CG = __builtin_amdgcn_mfma_f32_16x16x32_bf16(ah, bl, acc##CG, 0, 0, 0); \
            acc##CG = __builtin_amdgcn_mfma_f32_16x16x32_bf16(al, bh, acc##CG, 0, 0, 0); }
            STEP(0) STEP(1) STEP(2) STEP(3)
#undef STEP
        }
#define EPI(ACC, CG) { \
        const int code_ = code0 + (CG) * 16 + (l & 15); \
        const float en_ = enorm_g[code_]; \
        float d_; \
        d_ = fmaf(-2.f, ACC[0], zn0 + en_); UPDR(d_, code_, b1_0, i1_0, b2_0) \
        d_ = fmaf(-2.f, ACC[1], zn1 + en_); UPDR(d_, code_, b1_1, i1_1, b2_1) \
        d_ = fmaf(-2.f, ACC[2], zn2 + en_); UPDR(d_, code_, b1_2, i1_2, b2_2) \
        d_ = fmaf(-2.f, ACC[3], zn3 + en_); UPDR(d_, code_, b1_3, i1_3, b2_3) }
        EPI(acc0, 0) EPI(acc1, 1) EPI(acc2, 2) EPI(acc3, 3)
#undef EPI
    }

    // ---- reduce over the 16 col-lanes (same g group) ----
    RED16(b1_0, i1_0, b2_0)
    RED16(b1_1, i1_1, b2_1)
    RED16(b1_2, i1_2, b2_2)
    RED16(b1_3, i1_3, b2_3)

    // ---- merge the two code-halves via LDS ----
    if (hf == 0 && (l & 15) == 0) {
        mb1[row0 + 0] = b1_0; mi1[row0 + 0] = i1_0; mb2[row0 + 0] = b2_0;
        mb1[row0 + 1] = b1_1; mi1[row0 + 1] = i1_1; mb2[row0 + 1] = b2_1;
        mb1[row0 + 2] = b1_2; mi1[row0 + 2] = i1_2; mb2[row0 + 2] = b2_2;
        mb1[row0 + 3] = b1_3; mi1[row0 + 3] = i1_3; mb2[row0 + 3] = b2_3;
    }
    __syncthreads();
    if (hf == 1 && (l & 15) == 0) {
        float* iout = idx_out + (size_t)blockIdx.x * 64;
        float* mout = margin_out + (size_t)blockIdx.x * 64;
#define FIN(B1, I1, B2, R) { \
        const int row_ = row0 + (R); \
        const float lob1 = mb1[row_]; const int loi1 = mi1[row_]; const float lob2 = mb2[row_]; \
        const bool hi_ = (B1 < lob1);  /* ties keep lo (smaller codes) */ \
        const float fb1 = hi_ ? B1 : lob1; \
        const int   fi1 = hi_ ? I1 : loi1; \
        const float fb2 = fminf(fminf(B2, lob2), fmaxf(B1, lob1)); \
        iout[row_] = (float)fi1; \
        mout[row_] = fb2 - fb1; }
        FIN(b1_0, i1_0, b2_0, 0)
        FIN(b1_1, i1_1, b2_1, 1)
        FIN(b1_2, i1_2, b2_2, 2)
        FIN(b1_3, i1_3, b2_3, 3)
#undef FIN
    }
}

// ---------------- kernel 2: exact fp32 fixup for near-tie rows ----------------
__global__ __launch_bounds__(256)
void fixup_kernel(const float* __restrict__ z, const float* __restrict__ emb,
                  const float* __restrict__ enorm_g, const float* __restrict__ margins,
                  float* __restrict__ idx_out) {
    const int w = threadIdx.x >> 6, l = threadIdx.x & 63;
    const int rbase = blockIdx.x * 256 + w * 64;
#pragma unroll 1
    for (int j = 0; j < 64; ++j) {
        const int r = rbase + j;
        if (margins[r] >= 2e-3f) continue;      // wave-uniform branch
        const float* zr = z + (size_t)r * 256;
        const float4 v = *reinterpret_cast<const float4*>(zr + l * 4);
        float zn = fmaf(v.x, v.x, fmaf(v.y, v.y, fmaf(v.z, v.z, v.w * v.w)));
#pragma unroll
        for (int o = 32; o > 0; o >>= 1) zn += __shfl_xor(zn, o);
        float b1 = 3.4e38f;
        int   i1 = 0;
#pragma unroll 1
        for (int t = 0; t < 16; ++t) {
            const int c = l + t * 64;           // ascending per lane
            const float* er = emb + (size_t)c * 256;
            float dot = 0.f;
#pragma unroll 4
            for (int d = 0; d < 256; d += 4) {
                const float4 zv = *reinterpret_cast<const float4*>(zr + d);
                const float4 ev = *reinterpret_cast<const float4*>(er + d);
                dot = fmaf(zv.x, ev.x, dot);
                dot = fmaf(zv.y, ev.y, dot);
                dot = fmaf(zv.z, ev.z, dot);
                dot = fmaf(zv.w, ev.w, dot);
            }
            const float dist = fmaf(-2.f, dot, zn + enorm_g[c]);
            if (dist < b1) { b1 = dist; i1 = c; }
        }
#pragma unroll
        for (int off = 1; off < 64; off <<= 1) {
            const float ov = __shfl_xor(b1, off);
            const int   oi = __shfl_xor(i1, off);
            if (ov < b1 || (ov == b1 && oi < i1)) { b1 = ov; i1 = oi; }
        }
        if (l == 0) idx_out[r] = (float)i1;
    }
}

// ---------------- kernel 3: gather + quantized output + loss partials ----------------
__global__ __launch_bounds__(256)
void gather_kernel(const float* __restrict__ z, const float* __restrict__ emb,
                   const float* __restrict__ idx_f, float* __restrict__ q_out,
                   float* __restrict__ partials) {
    const int wv = threadIdx.x >> 6, ln = threadIdx.x & 63;
    float lsum = 0.f;
#pragma unroll
    for (int i = 0; i < 16; ++i) {
        const size_t row = (size_t)blockIdx.x * 64 + i * 4 + wv;
        const int kidx = (int)idx_f[row];
        const float4 e4 = *reinterpret_cast<const float4*>(emb + (size_t)kidx * 256 + ln * 4);
        const float4 z4 = *reinterpret_cast<const float4*>(z + row * 256 + ln * 4);
        *reinterpret_cast<float4*>(q_out + row * 256 + ln * 4) = e4;  // quantized_st == quantized
        const float dx = e4.x - z4.x, dy = e4.y - z4.y, dz = e4.z - z4.z, dw = e4.w - z4.w;
        lsum += dx * dx + dy * dy + dz * dz + dw * dw;
    }
#pragma unroll
    for (int off = 32; off > 0; off >>= 1) lsum += __shfl_xor(lsum, off);
    __shared__ float red[4];
    if (ln == 0) red[wv] = lsum;
    __syncthreads();
    if (threadIdx.x == 0) partials[blockIdx.x] = red[0] + red[1] + red[2] + red[3];
}

// ---------------- kernel 4: deterministic loss reduction ----------------
__global__ __launch_bounds__(256)
void loss_kernel(const float* __restrict__ partials, float* __restrict__ loss_out) {
    const int tid = threadIdx.x;
    float s = partials[tid] + partials[tid + 256] + partials[tid + 512] + partials[tid + 768];
#pragma unroll
    for (int off = 32; off > 0; off >>= 1) s += __shfl_xor(s, off);
    __shared__ float red[4];
    if ((tid & 63) == 0) red[tid >> 6] = s;
    __syncthreads();
    if (tid == 0)
        loss_out[0] = (red[0] + red[1] + red[2] + red[3]) * (1.25f / 16777216.0f);
}

extern "C" void kernel_launch(void* const* d_in, const int* in_sizes, int n_in,
                              void* d_out, int out_size, void* d_ws, size_t ws_size,
                              hipStream_t stream) {
    const float* z   = (const float*)d_in[0];
    const float* emb = (const float*)d_in[1];
    float* out      = (float*)d_out;
    float* q_out    = out;                       // 16,777,216 floats
    float* loss_out = out + 16777216;            // 1 float
    float* idx_out  = out + 16777217;            // 65,536 floats
    float* enorm    = (float*)d_ws;              // 1024 f32
    float* partials = (float*)d_ws + 1024;       // 1024 f32
    // scratch inside the q region (fully rewritten by gather afterwards):
    unsigned short* eh_g = (unsigned short*)q_out;            // 512 KB
    unsigned short* el_g = eh_g + 262144;                      // 512 KB
    float* margins = (float*)(el_g + 262144);                  // 256 KB

    eprep_kernel<<<1024, 256, 0, stream>>>(emb, eh_g, el_g, enorm);
    argmin_kernel<<<1024, 512, 0, stream>>>(z, eh_g, el_g, enorm, idx_out, margins);
    fixup_kernel<<<256, 256, 0, stream>>>(z, emb, enorm, margins, idx_out);
    gather_kernel<<<1024, 256, 0, stream>>>(z, emb, idx_out, q_out, partials);
    loss_kernel<<<1, 256, 0, stream>>>(partials, loss_out);
}

// Round 10
// 408.817 us; speedup vs baseline: 1.7406x; 1.7406x over previous
//
#include <hip/hip_runtime.h>
#include <stdint.h>

// VectorQuantizer — z:(16,256,64,64) f32 -> 65536 rows of 256; emb:(1024,256) f32.
// d_out: q[16777216] | vq_loss[1] | idx_as_float[65536]
//
// R10: MFMA argmin restructured as a real GEMM: B (eh/el) staged to LDS via
// global_load_lds (streamed, double-buffered, counted vmcnt(4), raw barriers),
// wave = 32 rows x 128 codes with 4 independent 32x32x16 acc chains.
// R9 failed because B came from global per-step (2 loads in flight, scattered
// lines, dependent MFMA chains -> both pipes idle). Fixup now worklist-driven.

typedef __attribute__((ext_vector_type(8))) short short8;
typedef __attribute__((ext_vector_type(16))) float f32x16;

#define THR_MARGIN 2e-3f

__device__ __forceinline__ unsigned short f2bf(float f) {
    const unsigned int x = __float_as_uint(f);
    return (unsigned short)((x + 0x7FFFu + ((x >> 16) & 1u)) >> 16);
}
__device__ __forceinline__ float bf2f(unsigned short h) {
    return __uint_as_float(((unsigned int)h) << 16);
}
__device__ __forceinline__ void gload16(const void* gp, void* lp) {
    __builtin_amdgcn_global_load_lds(
        (const __attribute__((address_space(1))) void*)gp,
        (__attribute__((address_space(3))) void*)lp, 16, 0, 0);
}

// ---------------- kernel 0: e prep — eh/el bf16 split + fp32 norms + wlcnt=0 ----
__global__ __launch_bounds__(256)
void eprep_kernel(const float* __restrict__ emb, unsigned short* __restrict__ eh_g,
                  unsigned short* __restrict__ el_g, float* __restrict__ enorm,
                  int* __restrict__ wlcnt) {
    const int code = blockIdx.x;
    const int t = threadIdx.x;
    if (code == 0 && t == 0) wlcnt[0] = 0;
    const float v = emb[code * 256 + t];
    const unsigned short h = f2bf(v);
    eh_g[code * 256 + t] = h;
    el_g[code * 256 + t] = f2bf(v - bf2f(h));
    float s = v * v;
#pragma unroll
    for (int o = 32; o > 0; o >>= 1) s += __shfl_xor(s, o);
    __shared__ float red[4];
    if ((t & 63) == 0) red[t >> 6] = s;
    __syncthreads();
    if (t == 0) enorm[code] = (red[0] + red[1]) + (red[2] + red[3]);
}

// ---------------- kernel 1: MFMA argmin (LDS-staged B, dbuf, counted vmcnt) ----
// 512 thr = 8 waves; block = 64 rows x 1024 codes (2 passes of 512).
// wave w: rowgroup rg=w&1 (32 rows), codegroup g=w>>1 (128 codes of the pass).
// Slice = [512 codes][K=16] hi+lo staged per iteration; 32 slices total.

#define STAGE(S, B) { \
    const int p_ = (S) >> 4; \
    const int ks_ = (S) & 15; \
    const size_t sb_ = (size_t)p_ * 131072 + ks_ * 16 + hi1 * 8; \
    const size_t c0_ = (size_t)((cd0      ) ^ hi1) * 256; \
    const size_t c1_ = (size_t)((cd0 + 256) ^ hi1) * 256; \
    gload16(eh_g + sb_ + c0_, &bsl[B][t * 8]); \
    gload16(eh_g + sb_ + c1_, &bsl[B][4096 + t * 8]); \
    gload16(el_g + sb_ + c0_, &bsl[B][8192 + t * 8]); \
    gload16(el_g + sb_ + c1_, &bsl[B][12288 + t * 8]); }

__global__ __launch_bounds__(512, 2)
void argmin_kernel(const float* __restrict__ z, const unsigned short* __restrict__ eh_g,
                   const unsigned short* __restrict__ el_g, const float* __restrict__ enorm_g,
                   float* __restrict__ idx_out, float* __restrict__ zn_g,
                   int* __restrict__ wl, int* __restrict__ wlcnt) {
    __shared__ unsigned short zh[16384];      // 32KB [row: 512B, kbyte ^ ((row&7)<<4)]
    __shared__ unsigned short zl[16384];      // 32KB
    __shared__ unsigned short bsl[2][16384];  // 2 x (h 16KB | l 16KB); [c^hi][hi][8hw]
    __shared__ float znbuf[64];
    __shared__ float m_b1[4][64];
    __shared__ int   m_i1[4][64];
    __shared__ float m_b2[4][64];

    const int t = threadIdx.x;
    const int w = t >> 6, l = t & 63;
    const int hi = l >> 5;           // k-half for MFMA frags
    const int l32 = l & 31;
    const int rg = w & 1;            // rowgroup (32 rows)
    const int cw = (w >> 1) << 7;    // codegroup base within pass (128 codes)
    const int hi1 = t & 1;           // staging lane k-half
    const int cd0 = t >> 1;          // staging dest code (round 0)

    const float* zblk = z + (size_t)blockIdx.x * 16384;

    // ---- A staging: fp32 -> bf16 hi/lo into swizzled LDS + per-row |z|^2 ----
    {
        const int row = t >> 3;
        const int kk0 = (t & 7) * 32;
        float ps = 0.f;
#pragma unroll
        for (int i = 0; i < 8; ++i) {
            const int kk = kk0 + i * 4;
            const float4 v = *reinterpret_cast<const float4*>(zblk + row * 256 + kk);
            ushort4 hv, lv;
            hv.x = f2bf(v.x); lv.x = f2bf(v.x - bf2f(hv.x));
            hv.y = f2bf(v.y); lv.y = f2bf(v.y - bf2f(hv.y));
            hv.z = f2bf(v.z); lv.z = f2bf(v.z - bf2f(hv.z));
            hv.w = f2bf(v.w); lv.w = f2bf(v.w - bf2f(hv.w));
            const int boff = row * 512 + ((kk << 1) ^ ((row & 7) << 4));
            *reinterpret_cast<ushort4*>((char*)zh + boff) = hv;
            *reinterpret_cast<ushort4*>((char*)zl + boff) = lv;
            ps = fmaf(v.x, v.x, fmaf(v.y, v.y, fmaf(v.z, v.z, fmaf(v.w, v.w, ps))));
        }
        ps += __shfl_xor(ps, 1);
        ps += __shfl_xor(ps, 2);
        ps += __shfl_xor(ps, 4);
        if ((t & 7) == 0) { znbuf[row] = ps; zn_g[blockIdx.x * 64 + row] = ps; }
    }

    STAGE(0, 0)
    __syncthreads();   // full drain: A-LDS + znbuf + slice 0 all ready

    f32x16 acc[4];
    float stb1[16]; int sti1[16]; float stb2[16];
#pragma unroll
    for (int r = 0; r < 16; ++r) { stb1[r] = 3.4e38f; sti1[r] = 0; stb2[r] = 3.4e38f; }
#pragma unroll
    for (int ct = 0; ct < 4; ++ct)
#pragma unroll
        for (int j = 0; j < 16; ++j) acc[ct][j] = 0.f;

    const int arow = (rg << 5) + l32;
    const int abyte = arow * 512;
    const int aswz = (arow & 7) << 4;

#pragma unroll 1
    for (int s = 0; s < 32; ++s) {
        const int b = s & 1;
        const int ks = s & 15;
        if (s < 31) {
            STAGE(s + 1, b ^ 1)
            asm volatile("s_waitcnt vmcnt(4)" ::: "memory");
        } else {
            asm volatile("s_waitcnt vmcnt(0)" ::: "memory");
        }
        __builtin_amdgcn_s_barrier();
        __builtin_amdgcn_sched_barrier(0);

        const short8 ah = *reinterpret_cast<const short8*>(
            (const char*)zh + abyte + ((ks * 32 + hi * 16) ^ aswz));
        const short8 al = *reinterpret_cast<const short8*>(
            (const char*)zl + abyte + ((ks * 32 + hi * 16) ^ aswz));
#pragma unroll
        for (int ct = 0; ct < 4; ++ct) {
            const int c = cw + (ct << 5) + l32;
            const int bi = ((c ^ hi) << 4) + (hi << 3);
            const short8 bh = *reinterpret_cast<const short8*>(&bsl[b][bi]);
            const short8 blo = *reinterpret_cast<const short8*>(&bsl[b][8192 + bi]);
            acc[ct] = __builtin_amdgcn_mfma_f32_32x32x16_bf16(ah, bh, acc[ct], 0, 0, 0);
            acc[ct] = __builtin_amdgcn_mfma_f32_32x32x16_bf16(ah, blo, acc[ct], 0, 0, 0);
            acc[ct] = __builtin_amdgcn_mfma_f32_32x32x16_bf16(al, bh, acc[ct], 0, 0, 0);
        }
        __builtin_amdgcn_sched_barrier(0);
        __builtin_amdgcn_s_barrier();

        if (ks == 15) {
            // ---- pass epilogue: dist, 4-way merge, fold into running state ----
            const int p = s >> 4;
            const int cb = (p << 9) + cw + l32;
            const float en0 = enorm_g[cb];
            const float en1 = enorm_g[cb + 32];
            const float en2 = enorm_g[cb + 64];
            const float en3 = enorm_g[cb + 96];
#pragma unroll
            for (int reg = 0; reg < 16; ++reg) {
                const int rl = (reg & 3) + ((reg >> 2) << 3) + (hi << 2);
                const float zr = znbuf[(rg << 5) + rl];
                const float v0 = fmaf(-2.f, acc[0][reg], zr + en0);
                const float v1 = fmaf(-2.f, acc[1][reg], zr + en1);
                const float v2 = fmaf(-2.f, acc[2][reg], zr + en2);
                const float v3 = fmaf(-2.f, acc[3][reg], zr + en3);
                float bb = v0; int bi = cb; float b2;
                if (v1 < bb) { b2 = bb; bb = v1; bi = cb + 32; } else b2 = v1;
                if (v2 < bb) { b2 = bb; bb = v2; bi = cb + 64; } else b2 = fminf(b2, v2);
                if (v3 < bb) { b2 = bb; bb = v3; bi = cb + 96; } else b2 = fminf(b2, v3);
                const float nb2 = fminf(fminf(stb2[reg], b2), fmaxf(stb1[reg], bb));
                if (bb < stb1[reg]) { stb1[reg] = bb; sti1[reg] = bi; }
                stb2[reg] = nb2;
            }
#pragma unroll
            for (int ct = 0; ct < 4; ++ct)
#pragma unroll
                for (int j = 0; j < 16; ++j) acc[ct][j] = 0.f;
        }
    }

    // ---- cross-lane reduce over the 32 col-lanes (per reg slot) ----
#pragma unroll
    for (int reg = 0; reg < 16; ++reg) {
#pragma unroll
        for (int o = 1; o < 32; o <<= 1) {
            const float ob1 = __shfl_xor(stb1[reg], o);
            const int   oi1 = __shfl_xor(sti1[reg], o);
            const float ob2 = __shfl_xor(stb2[reg], o);
            const float nb2 = fminf(fminf(stb2[reg], ob2), fmaxf(stb1[reg], ob1));
            if (ob1 < stb1[reg] || (ob1 == stb1[reg] && oi1 < sti1[reg])) {
                stb1[reg] = ob1; sti1[reg] = oi1;
            }
            stb2[reg] = nb2;
        }
    }
    if (l32 == 0) {
        const int g = w >> 1;
#pragma unroll
        for (int reg = 0; reg < 16; ++reg) {
            const int rl = (reg & 3) + ((reg >> 2) << 3) + (hi << 2);
            const int rowb = (rg << 5) + rl;
            m_b1[g][rowb] = stb1[reg];
            m_i1[g][rowb] = sti1[reg];
            m_b2[g][rowb] = stb2[reg];
        }
    }
    __syncthreads();
    if (t < 64) {
        float b1 = m_b1[0][t]; int i1 = m_i1[0][t]; float b2 = m_b2[0][t];
#pragma unroll
        for (int g = 1; g < 4; ++g) {
            const float ob1 = m_b1[g][t]; const int oi1 = m_i1[g][t]; const float ob2 = m_b2[g][t];
            const float nb2 = fminf(fminf(b2, ob2), fmaxf(b1, ob1));
            if (ob1 < b1 || (ob1 == b1 && oi1 < i1)) { b1 = ob1; i1 = oi1; }
            b2 = nb2;
        }
        const int grow = blockIdx.x * 64 + t;
        idx_out[grow] = (float)i1;
        if (b2 - b1 < THR_MARGIN) {
            const int pos = atomicAdd(wlcnt, 1);
            wl[pos] = grow;
        }
    }
}

// ---------------- kernel 2: exact fp32 fixup (worklist-driven) ----------------
__global__ __launch_bounds__(256)
void fixup_kernel(const float* __restrict__ z, const float* __restrict__ emb,
                  const float* __restrict__ enorm_g, const float* __restrict__ zn_g,
                  const int* __restrict__ wl, const int* __restrict__ wlcnt,
                  float* __restrict__ idx_out) {
    const int wid = blockIdx.x * 4 + (threadIdx.x >> 6);
    const int l = threadIdx.x & 63;
    int n = wlcnt[0];
    if (n > 65536) n = 65536;
#pragma unroll 1
    for (int i = wid; i < n; i += 4096) {
        const int r = wl[i];
        const float* zr = z + (size_t)r * 256;
        const float zn = zn_g[r];
        float b1 = 3.4e38f;
        int   i1 = 0;
#pragma unroll 1
        for (int tt = 0; tt < 16; ++tt) {
            const int c = l + tt * 64;           // ascending per lane
            const float* er = emb + (size_t)c * 256;
            float dot = 0.f;
#pragma unroll 4
            for (int d = 0; d < 256; d += 4) {
                const float4 zv = *reinterpret_cast<const float4*>(zr + d);
                const float4 ev = *reinterpret_cast<const float4*>(er + d);
                dot = fmaf(zv.x, ev.x, dot);
                dot = fmaf(zv.y, ev.y, dot);
                dot = fmaf(zv.z, ev.z, dot);
                dot = fmaf(zv.w, ev.w, dot);
            }
            const float dist = fmaf(-2.f, dot, zn + enorm_g[c]);
            if (dist < b1) { b1 = dist; i1 = c; }
        }
#pragma unroll
        for (int off = 1; off < 64; off <<= 1) {
            const float ov = __shfl_xor(b1, off);
            const int   oi = __shfl_xor(i1, off);
            if (ov < b1 || (ov == b1 && oi < i1)) { b1 = ov; i1 = oi; }
        }
        if (l == 0) idx_out[r] = (float)i1;
    }
}

// ---------------- kernel 3: gather + quantized output + loss partials ----------
__global__ __launch_bounds__(256)
void gather_kernel(const float* __restrict__ z, const float* __restrict__ emb,
                   const float* __restrict__ idx_f, float* __restrict__ q_out,
                   float* __restrict__ partials) {
    const int wv = threadIdx.x >> 6, ln = threadIdx.x & 63;
    float lsum = 0.f;
#pragma unroll
    for (int i = 0; i < 16; ++i) {
        const size_t row = (size_t)blockIdx.x * 64 + i * 4 + wv;
        const int kidx = (int)idx_f[row];
        const float4 e4 = *reinterpret_cast<const float4*>(emb + (size_t)kidx * 256 + ln * 4);
        const float4 z4 = *reinterpret_cast<const float4*>(z + row * 256 + ln * 4);
        *reinterpret_cast<float4*>(q_out + row * 256 + ln * 4) = e4;  // quantized_st == quantized
        const float dx = e4.x - z4.x, dy = e4.y - z4.y, dz = e4.z - z4.z, dw = e4.w - z4.w;
        lsum += dx * dx + dy * dy + dz * dz + dw * dw;
    }
#pragma unroll
    for (int off = 32; off > 0; off >>= 1) lsum += __shfl_xor(lsum, off);
    __shared__ float red[4];
    if (ln == 0) red[wv] = lsum;
    __syncthreads();
    if (threadIdx.x == 0) partials[blockIdx.x] = red[0] + red[1] + red[2] + red[3];
}

// ---------------- kernel 4: deterministic loss reduction ----------------------
__global__ __launch_bounds__(256)
void loss_kernel(const float* __restrict__ partials, float* __restrict__ loss_out) {
    const int tid = threadIdx.x;
    float s = partials[tid] + partials[tid + 256] + partials[tid + 512] + partials[tid + 768];
#pragma unroll
    for (int off = 32; off > 0; off >>= 1) s += __shfl_xor(s, off);
    __shared__ float red[4];
    if ((tid & 63) == 0) red[tid >> 6] = s;
    __syncthreads();
    if (tid == 0)
        loss_out[0] = (red[0] + red[1] + red[2] + red[3]) * (1.25f / 16777216.0f);
}

extern "C" void kernel_launch(void* const* d_in, const int* in_sizes, int n_in,
                              void* d_out, int out_size, void* d_ws, size_t ws_size,
                              hipStream_t stream) {
    const float* z   = (const float*)d_in[0];
    const float* emb = (const float*)d_in[1];
    float* out      = (float*)d_out;
    float* q_out    = out;                       // 16,777,216 floats
    float* loss_out = out + 16777216;            // 1 float
    float* idx_out  = out + 16777217;            // 65,536 floats
    float* enorm    = (float*)d_ws;              // 1024 f32
    float* partials = (float*)d_ws + 1024;       // 1024 f32
    // scratch inside the q region (fully rewritten by gather afterwards):
    unsigned short* eh_g = (unsigned short*)q_out;          // 512 KB
    unsigned short* el_g = eh_g + 131072 * 2;               // 512 KB (el @ float ofs 131072)
    float* zn_g  = q_out + 262144;                          // 256 KB
    int*   wl    = (int*)(q_out + 327680);                  // 256 KB
    int*   wlcnt = (int*)(q_out + 393216);                  // 4 B

    eprep_kernel<<<1024, 256, 0, stream>>>(emb, eh_g, el_g, enorm, wlcnt);
    argmin_kernel<<<1024, 512, 0, stream>>>(z, eh_g, el_g, enorm, idx_out, zn_g, wl, wlcnt);
    fixup_kernel<<<1024, 256, 0, stream>>>(z, emb, enorm, zn_g, wl, wlcnt, idx_out);
    gather_kernel<<<1024, 256, 0, stream>>>(z, emb, idx_out, q_out, partials);
    loss_kernel<<<1, 256, 0, stream>>>(partials, loss_out);
}